// Round 1
// 136.712 us; speedup vs baseline: 1.0393x; 1.0393x over previous
//
#include <hip/hip_runtime.h>
#include <hip/hip_bf16.h>

#define Bsz 16
#define Nn  1024
#define Ff  256
#define ALPHA 0.2f
#define NEG_BIG -9.0e15f

typedef __attribute__((ext_vector_type(8))) short short8;
typedef __attribute__((ext_vector_type(4))) float f32x4;
typedef __attribute__((ext_vector_type(4))) unsigned short ushort4_t;

__device__ __forceinline__ unsigned short f2bf(float x) {
    union { __hip_bfloat16 b; unsigned short u; } cv;
    cv.b = __float2bfloat16(x);
    return cv.u;
}

// ---- K0: w1 = W@a1 ; w2 = W@a2  (64 blocks, wave per output f) ------------
__global__ __launch_bounds__(256) void gat_prep(
    const float* __restrict__ W, const float* __restrict__ a,
    float* __restrict__ w1, float* __restrict__ w2)
{
    const int t = threadIdx.x, w = t >> 6, ln = t & 63;
    __shared__ float a1s[Ff], a2s[Ff];
    a1s[t] = a[t];
    a2s[t] = a[Ff + t];
    __syncthreads();
    const int f = blockIdx.x * 4 + w;
    float s1 = 0.f, s2 = 0.f;
    #pragma unroll
    for (int c = 0; c < 4; c++) {
        const int o = ln + 64 * c;
        const float wv = W[(size_t)f * Ff + o];
        s1 += wv * a1s[o];
        s2 += wv * a2s[o];
    }
    #pragma unroll
    for (int off = 1; off < 64; off <<= 1) {
        s1 += __shfl_xor(s1, off, 64);
        s2 += __shfl_xor(s2, off, 64);
    }
    if (ln == 0) { w1[f] = s1; w2[f] = s2; }
}

// ---- K1: pack/transpose h,W to bf16 K-tiles + fused f1/f2 -----------------
// tile stride 260 floats = 1040 B (16B-aligned rows, 1040 % 128 == 16):
// float4 LDS writes are single conflict-free ds_write_b128 (was 4 scalar
// stores x 4-way conflict at stride 257).
__global__ __launch_bounds__(256) void pack_f(
    const float* __restrict__ h, const float* __restrict__ W,
    const float* __restrict__ w1, const float* __restrict__ w2,
    unsigned short* __restrict__ hK, unsigned short* __restrict__ WK,
    float* __restrict__ f1, float* __restrict__ f2)
{
    __shared__ __align__(16) float tile[32][260];
    const int id = blockIdx.x, t = threadIdx.x, w = t >> 6, ln = t & 63;
    const bool isH = (id < 512);
    const float* src;
    unsigned short* dst;
    int grow0 = 0;
    if (isH) {
        const int b = id >> 5, kt = id & 31;
        grow0 = b * Nn + kt * 32;
        src = h + (size_t)grow0 * Ff;
        dst = hK + ((size_t)(b * 32 + kt)) * 8192;
    } else {
        const int ft = id - 512;
        src = W + (size_t)ft * 32 * Ff;
        dst = WK + (size_t)ft * 8192;
    }
    #pragma unroll
    for (int rr = 0; rr < 8; rr++) {
        const int row = rr * 4 + w;
        const int col = ln * 4;
        *(float4*)&tile[row][col] = *(const float4*)&src[row * Ff + col];
    }
    __syncthreads();

    unsigned* d32 = (unsigned*)dst;
    #pragma unroll
    for (int k = 0; k < 16; k++) {
        const int fidx = k * 256 + t;
        const int o = fidx >> 4, q = fidx & 15;
        const unsigned lo = f2bf(tile[2 * q][o]);
        const unsigned hi = f2bf(tile[2 * q + 1][o]);
        d32[fidx] = lo | (hi << 16);
    }

    if (isH) {
        float w1r[4], w2r[4];
        #pragma unroll
        for (int c = 0; c < 4; c++) {
            w1r[c] = w1[ln + 64 * c];
            w2r[c] = w2[ln + 64 * c];
        }
        #pragma unroll
        for (int rr = 0; rr < 8; rr++) {
            const int row = rr * 4 + w;
            float s1 = 0.f, s2 = 0.f;
            #pragma unroll
            for (int c = 0; c < 4; c++) {
                const float hv = tile[row][ln + 64 * c];
                s1 += hv * w1r[c];
                s2 += hv * w2r[c];
            }
            #pragma unroll
            for (int off = 1; off < 64; off <<= 1) {
                s1 += __shfl_xor(s1, off, 64);
                s2 += __shfl_xor(s2, off, 64);
            }
            if (ln == 0) { f1[grow0 + row] = s1; f2[grow0 + row] = s2; }
        }
    }
}

// ---- K2: softmax -> G = P@h (MFMA) -> out = elu(G@W) (MFMA), TI=32 --------
// 16 waves (1024 thr), 64 KiB LDS -> 2 blocks/CU = 32 waves/CU (100% occ cap,
// was 50% at 512 thr). Phase A: wave owns ONE row-pair (2w, 2w+1).
// Phase B/C: wave owns a 16-col n-slice x BOTH m-halves -> every hK/WK B-frag
// still loaded exactly once per block. VGPR must stay <=64 for 8 waves/SIMD.
#define TI 32
__global__ __launch_bounds__(1024, 8) void gat_attn(
    const int* __restrict__ adj,
    const float* __restrict__ f1, const float* __restrict__ f2,
    const unsigned short* __restrict__ hK, const unsigned short* __restrict__ WK,
    float* __restrict__ out)
{
    // 64 KB exactly: P (swizzled, stride 1024) in phases A/B; G (stride 264) in C
    __shared__ __align__(16) unsigned short pbf[TI * 1024];
    const int t = threadIdx.x, w = t >> 6, ln = t & 63;   // 16 waves
    const int m = ln & 15, quad = ln >> 4;
    const int bid = blockIdx.x;
    const int b  = 2 * (bid & 7) + ((bid >> 3) & 1);      // XCD-local batches
    const int i0 = (bid >> 4) * TI;

    float4 f2r[4];
    #pragma unroll
    for (int c = 0; c < 4; c++)
        f2r[c] = *(const float4*)&f2[b * Nn + 256 * c + 4 * ln];

    // ---- Phase A: wave w owns rows 2w, 2w+1 ----
    const int r0 = 2 * w, r1 = r0 + 1;
    const int grb = b * Nn + i0 + r0;
    const int* aptr = adj + (size_t)grb * Nn;
    int4 av0[4], av1[4];
    #pragma unroll
    for (int c = 0; c < 4; c++) {
        av0[c] = *(const int4*)&aptr[c * 256 + 4 * ln];
        av1[c] = *(const int4*)&aptr[Nn + c * 256 + 4 * ln];
    }
    const float fi0 = f1[grb], fi1 = f1[grb + 1];
    float e0[16], e1[16];
    float mx0 = -INFINITY, mx1 = -INFINITY;
    #pragma unroll
    for (int c = 0; c < 4; c++) {
        const float4 fv = f2r[c];
        float x, y;
        // lrelu(x) = max(x, 0.2x) since 0 < alpha < 1
        x = fi0 + fv.x; x = fmaxf(x, ALPHA * x); x = av0[c].x > 0 ? x : NEG_BIG; e0[4*c+0] = x;
        y = fi0 + fv.y; y = fmaxf(y, ALPHA * y); y = av0[c].y > 0 ? y : NEG_BIG; e0[4*c+1] = y;
        mx0 = fmaxf(fmaxf(x, y), mx0);                         // v_max3
        x = fi0 + fv.z; x = fmaxf(x, ALPHA * x); x = av0[c].z > 0 ? x : NEG_BIG; e0[4*c+2] = x;
        y = fi0 + fv.w; y = fmaxf(y, ALPHA * y); y = av0[c].w > 0 ? y : NEG_BIG; e0[4*c+3] = y;
        mx0 = fmaxf(fmaxf(x, y), mx0);
        x = fi1 + fv.x; x = fmaxf(x, ALPHA * x); x = av1[c].x > 0 ? x : NEG_BIG; e1[4*c+0] = x;
        y = fi1 + fv.y; y = fmaxf(y, ALPHA * y); y = av1[c].y > 0 ? y : NEG_BIG; e1[4*c+1] = y;
        mx1 = fmaxf(fmaxf(x, y), mx1);
        x = fi1 + fv.z; x = fmaxf(x, ALPHA * x); x = av1[c].z > 0 ? x : NEG_BIG; e1[4*c+2] = x;
        y = fi1 + fv.w; y = fmaxf(y, ALPHA * y); y = av1[c].w > 0 ? y : NEG_BIG; e1[4*c+3] = y;
        mx1 = fmaxf(fmaxf(x, y), mx1);
    }
    #pragma unroll
    for (int off = 1; off < 64; off <<= 1) {
        mx0 = fmaxf(mx0, __shfl_xor(mx0, off, 64));
        mx1 = fmaxf(mx1, __shfl_xor(mx1, off, 64));
    }
    float s0 = 0.f, s1 = 0.f;
    #pragma unroll
    for (int c = 0; c < 16; c++) {
        e0[c] = __expf(e0[c] - mx0); s0 += e0[c];   // all-masked row -> uniform
        e1[c] = __expf(e1[c] - mx1); s1 += e1[c];
    }
    #pragma unroll
    for (int off = 1; off < 64; off <<= 1) {
        s0 += __shfl_xor(s0, off, 64);
        s1 += __shfl_xor(s1, off, 64);
    }
    const float ri0 = 1.f / s0, ri1 = 1.f / s1;
    #pragma unroll
    for (int c = 0; c < 4; c++) {
        const int j = 256 * c + 4 * ln;
        ushort4_t v0 = { f2bf(e0[4*c] * ri0), f2bf(e0[4*c+1] * ri0),
                         f2bf(e0[4*c+2] * ri0), f2bf(e0[4*c+3] * ri0) };
        ushort4_t v1 = { f2bf(e1[4*c] * ri1), f2bf(e1[4*c+1] * ri1),
                         f2bf(e1[4*c+2] * ri1), f2bf(e1[4*c+3] * ri1) };
        *(ushort4_t*)&pbf[r0 * 1024 + (j ^ ((r0 & 7) << 3))] = v0;
        *(ushort4_t*)&pbf[r1 * 1024 + (j ^ ((r1 & 7) << 3))] = v1;
    }
    __syncthreads();

    // ---- Phase B: G = P @ h_b ; wave n-slice 16, both m-halves ----
    const int n0 = w * 16;
    const unsigned short* hKb = hK + (size_t)b * 32 * 8192;
    const int arow0 = m * 1024, arow1 = (16 + m) * 1024;
    const int asw = (m & 7) << 3;
    #define AF0(kt) (*(const short8*)&pbf[arow0 + ((((kt) * 32) + quad * 8) ^ asw)])
    #define AF1(kt) (*(const short8*)&pbf[arow1 + ((((kt) * 32) + quad * 8) ^ asw)])
    #define BF(kt)  (*(const short8*)&hKb[(size_t)(kt) * 8192 + (n0 + m) * 32 + quad * 8])

    f32x4 acc0 = {0.f,0.f,0.f,0.f}, acc1 = acc0;
    short8 a0c = AF0(0), a1c = AF1(0);
    short8 bc = BF(0), bn = BF(1);
    #pragma unroll
    for (int kt = 0; kt < 32; kt++) {
        short8 bnn = bc, a0n = a0c, a1n = a1c;
        if (kt + 2 < 32) bnn = BF(kt + 2);
        if (kt + 1 < 32) { a0n = AF0(kt + 1); a1n = AF1(kt + 1); }
        acc0 = __builtin_amdgcn_mfma_f32_16x16x32_bf16(a0c, bc, acc0, 0, 0, 0);
        acc1 = __builtin_amdgcn_mfma_f32_16x16x32_bf16(a1c, bc, acc1, 0, 0, 0);
        a0c = a0n; a1c = a1n; bc = bn; bn = bnn;
    }

    __syncthreads();   // P dead; reuse pbf for G (stride 264)
    #pragma unroll
    for (int reg = 0; reg < 4; reg++) {
        pbf[(quad * 4 + reg) * 264 + n0 + m]      = f2bf(acc0[reg]);
        pbf[(16 + quad * 4 + reg) * 264 + n0 + m] = f2bf(acc1[reg]);
    }
    __syncthreads();

    // ---- Phase C: out = elu( G @ W ) ; same wave mapping ----
    #define GA0(kt) (*(const short8*)&pbf[m * 264 + (kt) * 32 + quad * 8])
    #define GA1(kt) (*(const short8*)&pbf[(16 + m) * 264 + (kt) * 32 + quad * 8])
    #define WB(kt)  (*(const short8*)&WK[(size_t)(kt) * 8192 + (n0 + m) * 32 + quad * 8])

    f32x4 c0 = {0.f,0.f,0.f,0.f}, c1 = c0;
    short8 ga0 = GA0(0), ga1 = GA1(0), wb = WB(0);
    #pragma unroll
    for (int kt = 0; kt < 8; kt++) {
        short8 ga0n = ga0, ga1n = ga1, wbn = wb;
        if (kt + 1 < 8) { ga0n = GA0(kt + 1); ga1n = GA1(kt + 1); wbn = WB(kt + 1); }
        c0 = __builtin_amdgcn_mfma_f32_16x16x32_bf16(ga0, wb, c0, 0, 0, 0);
        c1 = __builtin_amdgcn_mfma_f32_16x16x32_bf16(ga1, wb, c1, 0, 0, 0);
        ga0 = ga0n; ga1 = ga1n; wb = wbn;
    }
    const size_t ob = (size_t)(b * Nn) + i0;
    #pragma unroll
    for (int reg = 0; reg < 4; reg++) {
        float v;
        v = c0[reg]; v = v > 0.f ? v : (__expf(v) - 1.f);
        out[(ob + quad * 4 + reg) * Ff + n0 + m] = v;
        v = c1[reg]; v = v > 0.f ? v : (__expf(v) - 1.f);
        out[(ob + 16 + quad * 4 + reg) * Ff + n0 + m] = v;
    }
}

extern "C" void kernel_launch(void* const* d_in, const int* in_sizes, int n_in,
                              void* d_out, int out_size, void* d_ws, size_t ws_size,
                              hipStream_t stream)
{
    const void* h   = d_in[0];
    const void* adj = d_in[1];
    const void* W   = d_in[2];
    const void* a   = d_in[3];
    for (int i = 0; i < n_in; i++) {
        if      (in_sizes[i] == Bsz * Nn * Ff) h   = d_in[i];
        else if (in_sizes[i] == Bsz * Nn * Nn) adj = d_in[i];
        else if (in_sizes[i] == Ff * Ff)       W   = d_in[i];
        else if (in_sizes[i] == 2 * Ff)        a   = d_in[i];
    }
    float* out = (float*)d_out;

    char*  wsb = (char*)d_ws;
    float* w1  = (float*)wsb;                                   // 1 KiB
    float* w2  = w1 + Ff;                                       // 1 KiB
    float* f1  = (float*)(wsb + 4096);                          // 64 KiB
    float* f2  = f1 + Bsz * Nn;                                 // 64 KiB
    unsigned short* hK = (unsigned short*)(wsb + 4096 + 2 * 65536);  // 8 MiB
    unsigned short* WK = hK + (size_t)Bsz * 32 * 8192;               // 128 KiB

    gat_prep<<<64, 256, 0, stream>>>((const float*)W, (const float*)a, w1, w2);
    pack_f<<<520, 256, 0, stream>>>((const float*)h, (const float*)W, w1, w2, hK, WK, f1, f2);
    gat_attn<<<Bsz * (Nn / TI), 1024, 0, stream>>>((const int*)adj, f1, f2, hK, WK, out);
}